// Round 1
// baseline (457.371 us; speedup 1.0000x reference)
//
#include <hip/hip_runtime.h>
#include <hip/hip_bf16.h>
#include <stdint.h>

#define MDIM 4096
#define NDIM 4096
#define KDIM 4096

typedef float f32x4 __attribute__((ext_vector_type(4)));
typedef short s16x8 __attribute__((ext_vector_type(8)));

__device__ __forceinline__ unsigned short f2bf(float x) {
  uint32_t u = __float_as_uint(x);
  uint32_t r = (u + 0x7fffu + ((u >> 16) & 1u)) >> 16;  // round-to-nearest-even
  return (unsigned short)r;
}
__device__ __forceinline__ float bf2f(unsigned short b) {
  return __uint_as_float(((uint32_t)b) << 16);
}

// ---------------- pre-pass 1: split A (fp32 [M][K]) -> A_hi, A_lo (bf16 [M][K])
__global__ __launch_bounds__(256) void split_a(const float* __restrict__ A,
                                               unsigned short* __restrict__ hi,
                                               unsigned short* __restrict__ lo) {
  size_t i = ((size_t)blockIdx.x * 256 + threadIdx.x) * 4;
  float4 v = *(const float4*)(A + i);
  ushort4 h, l;
  h.x = f2bf(v.x); l.x = f2bf(v.x - bf2f(h.x));
  h.y = f2bf(v.y); l.y = f2bf(v.y - bf2f(h.y));
  h.z = f2bf(v.z); l.z = f2bf(v.z - bf2f(h.z));
  h.w = f2bf(v.w); l.w = f2bf(v.w - bf2f(h.w));
  *(ushort4*)(hi + i) = h;
  *(ushort4*)(lo + i) = l;
}

// ---------------- pre-pass 2: split + transpose B (fp32 [K][N]) -> B_hiT, B_loT (bf16 [N][K])
__global__ __launch_bounds__(256) void split_bt(const float* __restrict__ B,
                                                unsigned short* __restrict__ hiT,
                                                unsigned short* __restrict__ loT) {
  __shared__ float tile[32][33];
  int n0 = blockIdx.x * 32, k0 = blockIdx.y * 32;
  int tx = threadIdx.x, ty = threadIdx.y;  // block (32,8)
#pragma unroll
  for (int i = 0; i < 32; i += 8)
    tile[ty + i][tx] = B[(size_t)(k0 + ty + i) * NDIM + n0 + tx];
  __syncthreads();
#pragma unroll
  for (int i = 0; i < 32; i += 8) {
    float x = tile[tx][ty + i];  // = B[k0+tx][n0+ty+i]
    unsigned short h = f2bf(x);
    unsigned short l = f2bf(x - bf2f(h));
    size_t o = (size_t)(n0 + ty + i) * KDIM + k0 + tx;
    hiT[o] = h;
    loT[o] = l;
  }
}

// ---------------- main GEMM: C = Ah*BhT^T + Ah*BlT^T + Al*BhT^T (bf16x3, fp32 accum)
// m97 structure: 128x128 tile, BK=32, 4 waves (2x2), 64x64 per wave,
// global_load_lds width-16 staging, mfma_f32_16x16x32_bf16.
#define GLDS(gp, lp)                                              \
  __builtin_amdgcn_global_load_lds(                               \
      (const __attribute__((address_space(1))) void*)(gp),        \
      (__attribute__((address_space(3))) void*)(lp), 16, 0, 0)

__global__ __launch_bounds__(256, 2) void gemm_bf16x3(
    const unsigned short* __restrict__ Ah, const unsigned short* __restrict__ Al,
    const unsigned short* __restrict__ BhT, const unsigned short* __restrict__ BlT,
    float* __restrict__ C) {
  // 4 tiles of [128][32] bf16 = 4 * 8KB = 32KB
  __shared__ __align__(16) unsigned short lds[4 * 128 * 32];
  unsigned short* sA_h = lds;
  unsigned short* sA_l = lds + 4096;
  unsigned short* sB_h = lds + 8192;
  unsigned short* sB_l = lds + 12288;

  const int tid  = threadIdx.x;
  const int lane = tid & 63;
  const int wave = tid >> 6;
  const int wm = wave >> 1, wn = wave & 1;
  const int bm = blockIdx.y, bn = blockIdx.x;

  // staging geometry: chunk c = it*256 + tid covers LDS bytes c*16;
  // element = c*8 -> row = c>>2, col = (c&3)*8.  iter1 = iter0 + 64 rows.
  const int r   = tid >> 2;
  const int col = (tid & 3) << 3;

  const unsigned short* a_h0 = Ah  + (size_t)(bm * 128 + r) * KDIM + col;
  const unsigned short* a_l0 = Al  + (size_t)(bm * 128 + r) * KDIM + col;
  const unsigned short* b_h0 = BhT + (size_t)(bn * 128 + r) * KDIM + col;
  const unsigned short* b_l0 = BlT + (size_t)(bn * 128 + r) * KDIM + col;
  const unsigned short* a_h1 = a_h0 + (size_t)64 * KDIM;
  const unsigned short* a_l1 = a_l0 + (size_t)64 * KDIM;
  const unsigned short* b_h1 = b_h0 + (size_t)64 * KDIM;
  const unsigned short* b_l1 = b_l0 + (size_t)64 * KDIM;

  // wave-uniform LDS dest bases (HW adds lane*16 bytes)
  const int dbase0 = (wave * 64) * 8;          // elements
  const int dbase1 = (256 + wave * 64) * 8;

  f32x4 acc[4][4] = {};

  const int fr = lane & 15;
  const int fq = lane >> 4;  // 0..3
  const int abase = (wm * 64 + fr) * 32 + fq * 8;  // element offset into A tiles
  const int bbase = (wn * 64 + fr) * 32 + fq * 8;

  for (int k0 = 0; k0 < KDIM; k0 += 32) {
    GLDS(a_h0 + k0, sA_h + dbase0);
    GLDS(a_h1 + k0, sA_h + dbase1);
    GLDS(a_l0 + k0, sA_l + dbase0);
    GLDS(a_l1 + k0, sA_l + dbase1);
    GLDS(b_h0 + k0, sB_h + dbase0);
    GLDS(b_h1 + k0, sB_h + dbase1);
    GLDS(b_l0 + k0, sB_l + dbase0);
    GLDS(b_l1 + k0, sB_l + dbase1);
    __syncthreads();  // drains vmcnt -> tiles resident

    s16x8 ah[4], al[4], bh[4], bl[4];
#pragma unroll
    for (int m = 0; m < 4; ++m) {
      ah[m] = *(const s16x8*)(sA_h + abase + m * 512);
      al[m] = *(const s16x8*)(sA_l + abase + m * 512);
    }
#pragma unroll
    for (int n = 0; n < 4; ++n) {
      bh[n] = *(const s16x8*)(sB_h + bbase + n * 512);
      bl[n] = *(const s16x8*)(sB_l + bbase + n * 512);
    }
#pragma unroll
    for (int m = 0; m < 4; ++m) {
#pragma unroll
      for (int n = 0; n < 4; ++n) {
        acc[m][n] = __builtin_amdgcn_mfma_f32_16x16x32_bf16(ah[m], bh[n], acc[m][n], 0, 0, 0);
        acc[m][n] = __builtin_amdgcn_mfma_f32_16x16x32_bf16(ah[m], bl[n], acc[m][n], 0, 0, 0);
        acc[m][n] = __builtin_amdgcn_mfma_f32_16x16x32_bf16(al[m], bh[n], acc[m][n], 0, 0, 0);
      }
    }
    __syncthreads();  // protect LDS before next stage
  }

  // epilogue: C/D layout col=lane&15, row=(lane>>4)*4+j  [verified m89/m91]
  float* Cp = C + (size_t)(bm * 128 + wm * 64) * NDIM + (bn * 128 + wn * 64);
#pragma unroll
  for (int m = 0; m < 4; ++m) {
#pragma unroll
    for (int n = 0; n < 4; ++n) {
#pragma unroll
      for (int j = 0; j < 4; ++j) {
        Cp[(size_t)(m * 16 + fq * 4 + j) * NDIM + n * 16 + fr] = acc[m][n][j];
      }
    }
  }
}

// ---------------- fallback (only if workspace too small): plain fp32 tiled GEMM
__global__ __launch_bounds__(1024) void gemm_fp32_fallback(const float* __restrict__ A,
                                                           const float* __restrict__ B,
                                                           float* __restrict__ C) {
  __shared__ float As[32][33];
  __shared__ float Bs[32][33];
  int tx = threadIdx.x, ty = threadIdx.y;
  int row = blockIdx.y * 32 + ty, colg = blockIdx.x * 32 + tx;
  float acc = 0.f;
  for (int k0 = 0; k0 < KDIM; k0 += 32) {
    As[ty][tx] = A[(size_t)row * KDIM + k0 + tx];
    Bs[ty][tx] = B[(size_t)(k0 + ty) * NDIM + colg];
    __syncthreads();
#pragma unroll 8
    for (int kk = 0; kk < 32; ++kk) acc += As[ty][kk] * Bs[kk][tx];
    __syncthreads();
  }
  C[(size_t)row * NDIM + colg] = acc;
}

extern "C" void kernel_launch(void* const* d_in, const int* in_sizes, int n_in,
                              void* d_out, int out_size, void* d_ws, size_t ws_size,
                              hipStream_t stream) {
  const float* A = (const float*)d_in[0];
  const float* B = (const float*)d_in[1];
  float* C = (float*)d_out;

  const size_t elems = (size_t)MDIM * KDIM;
  const size_t need = 4 * elems * sizeof(unsigned short);  // 128 MB
  if (ws_size < need) {
    gemm_fp32_fallback<<<dim3(NDIM / 32, MDIM / 32), dim3(32, 32), 0, stream>>>(A, B, C);
    return;
  }

  unsigned short* Ah  = (unsigned short*)d_ws;
  unsigned short* Al  = Ah + elems;
  unsigned short* BhT = Al + elems;
  unsigned short* BlT = BhT + elems;

  split_a<<<(int)(elems / (256 * 4)), 256, 0, stream>>>(A, Ah, Al);
  split_bt<<<dim3(NDIM / 32, KDIM / 32), dim3(32, 8), 0, stream>>>(B, BhT, BlT);
  gemm_bf16x3<<<dim3(NDIM / 128, MDIM / 128), 256, 0, stream>>>(Ah, Al, BhT, BlT, C);
}

// Round 2
// 438.786 us; speedup vs baseline: 1.0424x; 1.0424x over previous
//
#include <hip/hip_runtime.h>
#include <hip/hip_bf16.h>
#include <stdint.h>

#define MDIM 4096
#define NDIM 4096
#define KDIM 4096
#define NT 192          // 12288 / 64 effective K-tiles (3 segments of 64)

typedef float f32x4 __attribute__((ext_vector_type(4)));
typedef short s16x8 __attribute__((ext_vector_type(8)));

__device__ __forceinline__ unsigned short f2bf(float x) {
  uint32_t u = __float_as_uint(x);
  uint32_t r = (u + 0x7fffu + ((u >> 16) & 1u)) >> 16;  // RNE
  return (unsigned short)r;
}
__device__ __forceinline__ float bf2f(unsigned short b) {
  return __uint_as_float(((uint32_t)b) << 16);
}

// ---------------- pre-pass 1: split A (fp32 [M][K]) -> A_hi, A_lo (bf16 [M][K])
__global__ __launch_bounds__(256) void split_a(const float* __restrict__ A,
                                               unsigned short* __restrict__ hi,
                                               unsigned short* __restrict__ lo) {
  size_t i = ((size_t)blockIdx.x * 256 + threadIdx.x) * 4;
  float4 v = *(const float4*)(A + i);
  ushort4 h, l;
  h.x = f2bf(v.x); l.x = f2bf(v.x - bf2f(h.x));
  h.y = f2bf(v.y); l.y = f2bf(v.y - bf2f(h.y));
  h.z = f2bf(v.z); l.z = f2bf(v.z - bf2f(h.z));
  h.w = f2bf(v.w); l.w = f2bf(v.w - bf2f(h.w));
  *(ushort4*)(hi + i) = h;
  *(ushort4*)(lo + i) = l;
}

// ---------------- pre-pass 2: split + transpose B (fp32 [K][N]) -> B_hiT, B_loT (bf16 [N][K])
__global__ __launch_bounds__(256) void split_bt(const float* __restrict__ B,
                                                unsigned short* __restrict__ hiT,
                                                unsigned short* __restrict__ loT) {
  __shared__ float tile[32][33];
  int n0 = blockIdx.x * 32, k0 = blockIdx.y * 32;
  int tx = threadIdx.x, ty = threadIdx.y;  // block (32,8)
#pragma unroll
  for (int i = 0; i < 32; i += 8)
    tile[ty + i][tx] = B[(size_t)(k0 + ty + i) * NDIM + n0 + tx];
  __syncthreads();
#pragma unroll
  for (int i = 0; i < 32; i += 8) {
    float x = tile[tx][ty + i];
    unsigned short h = f2bf(x);
    unsigned short l = f2bf(x - bf2f(h));
    size_t o = (size_t)(n0 + ty + i) * KDIM + k0 + tx;
    hiT[o] = h;
    loT[o] = l;
  }
}

// ---------------- main GEMM: single bf16 GEMM, effective K = 12288 via piecewise
// sources {Ah,Al,Ah} x {BhT,BhT,BlT}. BM=256,BN=128,BK=64, 8 waves (4x2),
// ring-of-3 LDS (144 KiB), counted vmcnt(6), XOR-swizzled LDS, setprio MFMA.
#define GLDS(gp, lp)                                              \
  __builtin_amdgcn_global_load_lds(                               \
      (const __attribute__((address_space(1))) void*)(gp),        \
      (__attribute__((address_space(3))) void*)(lp), 16, 0, 0)

#define BARRIER() asm volatile("s_barrier" ::: "memory")
#define WAITVM6() asm volatile("s_waitcnt vmcnt(6)" ::: "memory")
#define WAITVM0() asm volatile("s_waitcnt vmcnt(0)" ::: "memory")

// buffer geometry (elements of ushort):
//   buf b at b*24576; A-tile [256 rows][64 k] at +0 (row*64), B-tile [128][64] at +16384
//   swizzle: 16B-granule slot s stored at s ^ (row & 7)

__global__ __launch_bounds__(512, 2) void gemm_k3(
    const unsigned short* __restrict__ Ah, const unsigned short* __restrict__ Al,
    const unsigned short* __restrict__ BhT, const unsigned short* __restrict__ BlT,
    float* __restrict__ C) {
  __shared__ __align__(16) unsigned short lds_[3 * 24576];  // 144 KiB

  const int tid = threadIdx.x;
  const int l   = tid & 63;
  const int wv  = tid >> 6;      // 0..7
  const int wm  = wv >> 1;       // 0..3  (row quarter)
  const int wn  = wv & 1;        // 0..1  (col half)
  const int fr  = l & 15;
  const int fq  = l >> 4;        // 0..3
  const int lrow  = l >> 3;                 // 0..7
  const int lslot = (l & 7) ^ lrow;         // pre-swizzled global slot
  const size_t lane_src_off = (size_t)lrow * 8192 + (size_t)lslot * 16;  // bytes

  // bijective XCD swizzle: nwg=512, 512%8==0
  const int bid = blockIdx.x;
  const int swz = (bid & 7) * 64 + (bid >> 3);
  const int bm = swz >> 5;       // 0..15  (M/256)
  const int bn = swz & 31;       // 0..31  (N/128)

  const char* pAh = (const char*)Ah;
  const char* pAl = (const char*)Al;
  const char* pBh = (const char*)BhT;
  const char* pBl = (const char*)BlT;

  f32x4 acc[4][4] = {};

  // ---- stage one part (part 0..3 = A rows, 4..5 = B rows) of tile tt ----
  auto stage = [&](int tt, int part) {
    const char* pA = (tt < 128) ? ((tt < 64) ? pAh : pAl) : pAh;
    const char* pB = (tt < 128) ? pBh : pBl;
    const size_t kbyte = (size_t)(tt & 63) * 128;
    unsigned short* lb = lds_ + (tt % 3) * 24576;
    if (part < 4) {
      const char* s = pA + (size_t)(bm * 256 + wv * 32 + part * 8) * 8192 + kbyte + lane_src_off;
      GLDS(s, lb + (wv * 32 + part * 8) * 64);
    } else {
      const int i = part - 4;
      const char* s = pB + (size_t)(bn * 128 + wv * 16 + i * 8) * 8192 + kbyte + lane_src_off;
      GLDS(s, lb + 16384 + (wv * 16 + i * 8) * 64);
    }
  };

  // ---- prologue: stage tiles 0,1 (6 instr each per wave) ----
#pragma unroll
  for (int p = 0; p < 6; ++p) stage(0, p);
#pragma unroll
  for (int p = 0; p < 6; ++p) stage(1, p);
  WAITVM6();   // tile 0's 6 loads drained
  BARRIER();

  const int arow = (wm * 64 + fr) * 64;          // element offset of frag row (A)
  const int brow = (wn * 64 + fr) * 64;          // (B)
  const int frx  = fr & 7;

  for (int t = 0; t < NT; ++t) {
    const int cbase = (t % 3) * 24576;
    const bool pf = (t + 2) < NT;
    s16x8 a[4], b[4];

    // ================= phase 0 : k-slice 0 =================
    {
      const int sl = ((0 * 4 + fq) ^ frx) * 8;
#pragma unroll
      for (int m = 0; m < 4; ++m)
        a[m] = *(const s16x8*)&lds_[cbase + arow + m * 1024 + sl];
#pragma unroll
      for (int n = 0; n < 4; ++n)
        b[n] = *(const s16x8*)&lds_[cbase + 16384 + brow + n * 1024 + sl];
    }
    if (pf) { stage(t + 2, 0); stage(t + 2, 1); stage(t + 2, 2); }
    BARRIER();
    __builtin_amdgcn_s_setprio(1);
#pragma unroll
    for (int m = 0; m < 4; ++m)
#pragma unroll
      for (int n = 0; n < 4; ++n)
        acc[m][n] = __builtin_amdgcn_mfma_f32_16x16x32_bf16(a[m], b[n], acc[m][n], 0, 0, 0);
    __builtin_amdgcn_s_setprio(0);
    BARRIER();

    // ================= phase 1 : k-slice 1 =================
    {
      const int sl = ((1 * 4 + fq) ^ frx) * 8;
#pragma unroll
      for (int m = 0; m < 4; ++m)
        a[m] = *(const s16x8*)&lds_[cbase + arow + m * 1024 + sl];
#pragma unroll
      for (int n = 0; n < 4; ++n)
        b[n] = *(const s16x8*)&lds_[cbase + 16384 + brow + n * 1024 + sl];
    }
    if (pf) { stage(t + 2, 3); stage(t + 2, 4); stage(t + 2, 5); }
    BARRIER();
    __builtin_amdgcn_s_setprio(1);
#pragma unroll
    for (int m = 0; m < 4; ++m)
#pragma unroll
      for (int n = 0; n < 4; ++n)
        acc[m][n] = __builtin_amdgcn_mfma_f32_16x16x32_bf16(a[m], b[n], acc[m][n], 0, 0, 0);
    __builtin_amdgcn_s_setprio(0);

    // counted drain: keep tile t+2's 6 loads in flight; drain tile t+1's
    if (t + 2 < NT) { WAITVM6(); }
    else if (t + 1 < NT) { WAITVM0(); }
    BARRIER();
  }

  // ---- epilogue: C/D layout col=lane&15, row=(lane>>4)*4+j ----
  float* Cp = C + (size_t)(bm * 256 + wm * 64) * NDIM + (bn * 128 + wn * 64);
#pragma unroll
  for (int m = 0; m < 4; ++m)
#pragma unroll
    for (int n = 0; n < 4; ++n)
#pragma unroll
      for (int j = 0; j < 4; ++j)
        Cp[(size_t)(m * 16 + fq * 4 + j) * NDIM + n * 16 + fr] = acc[m][n][j];
}

// ---------------- fallback: plain fp32 tiled GEMM (ws too small) ----------------
__global__ __launch_bounds__(1024) void gemm_fp32_fallback(const float* __restrict__ A,
                                                           const float* __restrict__ B,
                                                           float* __restrict__ C) {
  __shared__ float As[32][33];
  __shared__ float Bs[32][33];
  int tx = threadIdx.x, ty = threadIdx.y;
  int row = blockIdx.y * 32 + ty, colg = blockIdx.x * 32 + tx;
  float acc = 0.f;
  for (int k0 = 0; k0 < KDIM; k0 += 32) {
    As[ty][tx] = A[(size_t)row * KDIM + k0 + tx];
    Bs[ty][tx] = B[(size_t)(k0 + ty) * NDIM + colg];
    __syncthreads();
#pragma unroll 8
    for (int kk = 0; kk < 32; ++kk) acc += As[ty][kk] * Bs[kk][tx];
    __syncthreads();
  }
  C[(size_t)row * NDIM + colg] = acc;
}

extern "C" void kernel_launch(void* const* d_in, const int* in_sizes, int n_in,
                              void* d_out, int out_size, void* d_ws, size_t ws_size,
                              hipStream_t stream) {
  const float* A = (const float*)d_in[0];
  const float* B = (const float*)d_in[1];
  float* C = (float*)d_out;

  const size_t elems = (size_t)MDIM * KDIM;
  const size_t need = 4 * elems * sizeof(unsigned short);  // 128 MB
  if (ws_size < need) {
    gemm_fp32_fallback<<<dim3(NDIM / 32, MDIM / 32), dim3(32, 32), 0, stream>>>(A, B, C);
    return;
  }

  unsigned short* Ah  = (unsigned short*)d_ws;
  unsigned short* Al  = Ah + elems;
  unsigned short* BhT = Al + elems;
  unsigned short* BlT = BhT + elems;

  split_a<<<(int)(elems / (256 * 4)), 256, 0, stream>>>(A, Ah, Al);
  split_bt<<<dim3(NDIM / 32, KDIM / 32), dim3(32, 8), 0, stream>>>(B, BhT, BlT);
  gemm_k3<<<dim3(512), dim3(512), 0, stream>>>(Ah, Al, BhT, BlT, C);
}

// Round 4
// 385.671 us; speedup vs baseline: 1.1859x; 1.1377x over previous
//
#include <hip/hip_runtime.h>
#include <hip/hip_bf16.h>
#include <stdint.h>

#define MDIM 4096
#define NDIM 4096
#define KDIM 4096
#define NT 192   // effective K = 12288 over 3 bf16 segments, BK = 64

typedef float f32x4 __attribute__((ext_vector_type(4)));
typedef short s16x8 __attribute__((ext_vector_type(8)));

__device__ __forceinline__ unsigned short f2bf(float x) {
  uint32_t u = __float_as_uint(x);
  uint32_t r = (u + 0x7fffu + ((u >> 16) & 1u)) >> 16;  // RNE
  return (unsigned short)r;
}
__device__ __forceinline__ float bf2f(unsigned short b) {
  return __uint_as_float(((uint32_t)b) << 16);
}

// ---------------- pre-pass 1: split A -> A_hi, A_lo (bf16 [M][K])
__global__ __launch_bounds__(256) void split_a(const float* __restrict__ A,
                                               unsigned short* __restrict__ hi,
                                               unsigned short* __restrict__ lo) {
  size_t i = ((size_t)blockIdx.x * 256 + threadIdx.x) * 4;
  float4 v = *(const float4*)(A + i);
  ushort4 h, l;
  h.x = f2bf(v.x); l.x = f2bf(v.x - bf2f(h.x));
  h.y = f2bf(v.y); l.y = f2bf(v.y - bf2f(h.y));
  h.z = f2bf(v.z); l.z = f2bf(v.z - bf2f(h.z));
  h.w = f2bf(v.w); l.w = f2bf(v.w - bf2f(h.w));
  *(ushort4*)(hi + i) = h;
  *(ushort4*)(lo + i) = l;
}

// ---------------- pre-pass 2: split + transpose B -> B_hiT, B_loT (bf16 [N][K])
__global__ __launch_bounds__(256) void split_bt(const float* __restrict__ B,
                                                unsigned short* __restrict__ hiT,
                                                unsigned short* __restrict__ loT) {
  __shared__ float tile[32][33];
  int n0 = blockIdx.x * 32, k0 = blockIdx.y * 32;
  int tx = threadIdx.x, ty = threadIdx.y;  // block (32,8)
#pragma unroll
  for (int i = 0; i < 32; i += 8)
    tile[ty + i][tx] = B[(size_t)(k0 + ty + i) * NDIM + n0 + tx];
  __syncthreads();
#pragma unroll
  for (int i = 0; i < 32; i += 8) {
    float x = tile[tx][ty + i];
    unsigned short h = f2bf(x);
    unsigned short l = f2bf(x - bf2f(h));
    size_t o = (size_t)(n0 + ty + i) * KDIM + k0 + tx;
    hiT[o] = h;
    loT[o] = l;
  }
}

// ---------------- main GEMM: 256x256 tile, BK=64, 8 waves (2M x 4N), per-wave 128x64.
// LDS ring-2 (128 KiB): A[buf][ks][128 ldsrows][128B], B likewise at +64KB.
// 2 matrix rows packed per 128B LDS row; 16B granule G stored at slot G^(ldsrow&7).
// Counted waits: vmcnt(4) at each K-half boundary, never 0 until tail.
#define GLDS(gp, lp)                                              \
  __builtin_amdgcn_global_load_lds(                               \
      (const __attribute__((address_space(1))) void*)(gp),        \
      (__attribute__((address_space(3))) void*)(lp), 16, 0, 0)

#define BARRIER() asm volatile("s_barrier" ::: "memory")
#define WAITVM4() asm volatile("s_waitcnt vmcnt(4)" ::: "memory")
#define WAITVM0() asm volatile("s_waitcnt vmcnt(0)" ::: "memory")

__global__ __launch_bounds__(512) void gemm_k3(
    const unsigned short* __restrict__ Ah, const unsigned short* __restrict__ Al,
    const unsigned short* __restrict__ BhT, const unsigned short* __restrict__ BlT,
    float* __restrict__ C) {
  __shared__ __align__(16) char lds_[131072];  // 128 KiB

  const int tid = threadIdx.x;
  const int l   = tid & 63;
  const int wv  = tid >> 6;   // 0..7
  const int wm  = wv >> 2;    // 0..1
  const int wn  = wv & 3;     // 0..3
  const int fr  = l & 15;
  const int fq  = l >> 4;

  // bijective XCD swizzle (256 blocks, 256%8==0)
  const int bid = blockIdx.x;
  const int swz = (bid & 7) * 32 + (bid >> 3);
  const int bm = swz >> 4, bn = swz & 15;

  // ---- staging lane geometry (linear LDS dest; inverse-swizzled global src) ----
  const int lG     = (l & 7) ^ (l >> 3);            // granule id in 128B LDS row
  const int g_radd = 2 * (l >> 3) + (lG >> 2);      // matrix-row offset in 16-row chunk
  const int g_col  = (lG & 3) * 16;                 // byte offset within 64B K-half
  const int row0a  = wv * 32;
  const int row0b  = wv * 32 + 16;

  // ---- read lane geometry (swizzled ds_read; same involution) ----
  const int slot  = (((fr & 1) << 2) | fq) ^ ((fr >> 1) & 7);
  const int laneA = ((wm * 128 + fr) >> 1) * 128 + slot * 16;
  const int laneB = 65536 + ((wn * 64 + fr) >> 1) * 128 + slot * 16;

  const char* cAh = (const char*)Ah;
  const char* cAl = (const char*)Al;
  const char* cBh = (const char*)BhT;
  const char* cBl = (const char*)BlT;
  const size_t aoff = (size_t)(bm * 256) * 8192;  // panel byte offsets (row stride 8 KB)
  const size_t boff = (size_t)(bn * 256) * 8192;

  f32x4 acc[8][4] = {};

  // ---- prologue: stage tile 0, units s=0 then s=1 (4 loads each) ----
  {
    const char* As = cAh + aoff;
    const char* Bs = cBh + boff;
#pragma unroll
    for (int s = 0; s < 2; ++s) {
      GLDS(As + (size_t)(row0a + g_radd) * 8192 + s * 64 + g_col, lds_ + s * 16384 + row0a * 64);
      GLDS(As + (size_t)(row0b + g_radd) * 8192 + s * 64 + g_col, lds_ + s * 16384 + row0b * 64);
      GLDS(Bs + (size_t)(row0a + g_radd) * 8192 + s * 64 + g_col, lds_ + 65536 + s * 16384 + row0a * 64);
      GLDS(Bs + (size_t)(row0b + g_radd) * 8192 + s * 64 + g_col, lds_ + 65536 + s * 16384 + row0b * 64);
    }
  }
  WAITVM4();  // tile0 ks0 resident; ks1 (4 loads) in flight
  BARRIER();

  for (int t = 0; t < NT; ++t) {
    const int cur = t & 1;
    const char* pa = lds_ + cur * 32768 + laneA;
    const char* pb = lds_ + cur * 32768 + laneB;

    const int Tn = t + 1;
    const char* An = ((Tn < 64) ? cAh : (Tn < 128) ? cAl : cAh) + aoff;
    const char* Bn = ((Tn < 128) ? cBh : cBl) + boff;
    const size_t kb = (size_t)(Tn & 63) * 128;
    char* dA = lds_ + (Tn & 1) * 32768;
    char* dB = dA + 65536;
    const bool pf = Tn < NT;

    s16x8 a[8], b[4];

    // ================= K-half 0 =================
#pragma unroll
    for (int m = 0; m < 8; ++m) a[m] = *(const s16x8*)(pa + m * 1024);
#pragma unroll
    for (int n = 0; n < 4; ++n) b[n] = *(const s16x8*)(pb + n * 1024);
    if (pf) {  // stage tile t+1, ks0, A-part
      GLDS(An + (size_t)(row0a + g_radd) * 8192 + kb + g_col, dA + row0a * 64);
      GLDS(An + (size_t)(row0b + g_radd) * 8192 + kb + g_col, dA + row0b * 64);
    }
    BARRIER();
    __builtin_amdgcn_s_setprio(1);
#pragma unroll
    for (int m = 0; m < 4; ++m)
#pragma unroll
      for (int n = 0; n < 4; ++n)
        acc[m][n] = __builtin_amdgcn_mfma_f32_16x16x32_bf16(a[m], b[n], acc[m][n], 0, 0, 0);
    __builtin_amdgcn_s_setprio(0);
    if (pf) {  // stage tile t+1, ks0, B-part
      GLDS(Bn + (size_t)(row0a + g_radd) * 8192 + kb + g_col, dB + row0a * 64);
      GLDS(Bn + (size_t)(row0b + g_radd) * 8192 + kb + g_col, dB + row0b * 64);
    }
    __builtin_amdgcn_s_setprio(1);
#pragma unroll
    for (int m = 4; m < 8; ++m)
#pragma unroll
      for (int n = 0; n < 4; ++n)
        acc[m][n] = __builtin_amdgcn_mfma_f32_16x16x32_bf16(a[m], b[n], acc[m][n], 0, 0, 0);
    __builtin_amdgcn_s_setprio(0);
    if (pf) { WAITVM4(); } else { WAITVM0(); }  // drain THIS tile's ks1 unit
    BARRIER();

    // ================= K-half 1 =================
#pragma unroll
    for (int m = 0; m < 8; ++m) a[m] = *(const s16x8*)(pa + 16384 + m * 1024);
#pragma unroll
    for (int n = 0; n < 4; ++n) b[n] = *(const s16x8*)(pb + 16384 + n * 1024);
    if (pf) {  // stage tile t+1, ks1, A-part
      GLDS(An + (size_t)(row0a + g_radd) * 8192 + kb + 64 + g_col, dA + 16384 + row0a * 64);
      GLDS(An + (size_t)(row0b + g_radd) * 8192 + kb + 64 + g_col, dA + 16384 + row0b * 64);
    }
    BARRIER();
    __builtin_amdgcn_s_setprio(1);
#pragma unroll
    for (int m = 0; m < 4; ++m)
#pragma unroll
      for (int n = 0; n < 4; ++n)
        acc[m][n] = __builtin_amdgcn_mfma_f32_16x16x32_bf16(a[m], b[n], acc[m][n], 0, 0, 0);
    __builtin_amdgcn_s_setprio(0);
    if (pf) {  // stage tile t+1, ks1, B-part
      GLDS(Bn + (size_t)(row0a + g_radd) * 8192 + kb + 64 + g_col, dB + 16384 + row0a * 64);
      GLDS(Bn + (size_t)(row0b + g_radd) * 8192 + kb + 64 + g_col, dB + 16384 + row0b * 64);
    }
    __builtin_amdgcn_s_setprio(1);
#pragma unroll
    for (int m = 4; m < 8; ++m)
#pragma unroll
      for (int n = 0; n < 4; ++n)
        acc[m][n] = __builtin_amdgcn_mfma_f32_16x16x32_bf16(a[m], b[n], acc[m][n], 0, 0, 0);
    __builtin_amdgcn_s_setprio(0);
    if (pf) { WAITVM4(); } else { WAITVM0(); }  // drain next tile's ks0 unit
    BARRIER();
  }

  // ---- epilogue: C/D layout col=lane&15, row=(lane>>4)*4+j ----
  float* Cp = C + (size_t)(bm * 256 + wm * 128) * NDIM + (bn * 256 + wn * 64);
#pragma unroll
  for (int m = 0; m < 8; ++m)
#pragma unroll
    for (int n = 0; n < 4; ++n)
#pragma unroll
      for (int j = 0; j < 4; ++j)
        Cp[(size_t)(m * 16 + fq * 4 + j) * NDIM + n * 16 + fr] = acc[m][n][j];
}

// ---------------- fallback: plain fp32 tiled GEMM (ws too small) ----------------
__global__ __launch_bounds__(1024) void gemm_fp32_fallback(const float* __restrict__ A,
                                                           const float* __restrict__ B,
                                                           float* __restrict__ C) {
  __shared__ float As[32][33];
  __shared__ float Bs[32][33];
  int tx = threadIdx.x, ty = threadIdx.y;
  int row = blockIdx.y * 32 + ty, colg = blockIdx.x * 32 + tx;
  float acc = 0.f;
  for (int k0 = 0; k0 < KDIM; k0 += 32) {
    As[ty][tx] = A[(size_t)row * KDIM + k0 + tx];
    Bs[ty][tx] = B[(size_t)(k0 + ty) * NDIM + colg];
    __syncthreads();
#pragma unroll 8
    for (int kk = 0; kk < 32; ++kk) acc += As[ty][kk] * Bs[kk][tx];
    __syncthreads();
  }
  C[(size_t)row * NDIM + colg] = acc;
}

extern "C" void kernel_launch(void* const* d_in, const int* in_sizes, int n_in,
                              void* d_out, int out_size, void* d_ws, size_t ws_size,
                              hipStream_t stream) {
  const float* A = (const float*)d_in[0];
  const float* B = (const float*)d_in[1];
  float* C = (float*)d_out;

  const size_t elems = (size_t)MDIM * KDIM;
  const size_t need = 4 * elems * sizeof(unsigned short);  // 128 MB
  if (ws_size < need) {
    gemm_fp32_fallback<<<dim3(NDIM / 32, MDIM / 32), dim3(32, 32), 0, stream>>>(A, B, C);
    return;
  }

  unsigned short* Ah  = (unsigned short*)d_ws;
  unsigned short* Al  = Ah + elems;
  unsigned short* BhT = Al + elems;
  unsigned short* BlT = BhT + elems;

  split_a<<<(int)(elems / (256 * 4)), 256, 0, stream>>>(A, Ah, Al);
  split_bt<<<dim3(NDIM / 32, KDIM / 32), dim3(32, 8), 0, stream>>>(B, BhT, BlT);
  gemm_k3<<<dim3(256), dim3(512), 0, stream>>>(Ah, Al, BhT, BlT, C);
}

// Round 6
// 363.316 us; speedup vs baseline: 1.2589x; 1.0615x over previous
//
#include <hip/hip_runtime.h>
#include <hip/hip_bf16.h>
#include <stdint.h>

#define MDIM 4096
#define NDIM 4096
#define KDIM 4096
#define NT 192   // effective K = 12288 over 3 bf16 segments, BK = 64

typedef float f32x4 __attribute__((ext_vector_type(4)));
typedef short s16x8 __attribute__((ext_vector_type(8)));

__device__ __forceinline__ unsigned short f2bf(float x) {
  uint32_t u = __float_as_uint(x);
  uint32_t r = (u + 0x7fffu + ((u >> 16) & 1u)) >> 16;  // RNE
  return (unsigned short)r;
}
__device__ __forceinline__ float bf2f(unsigned short b) {
  return __uint_as_float(((uint32_t)b) << 16);
}

// ---------------- pre-pass 1: split A -> A_hi, A_lo (bf16 [M][K])
__global__ __launch_bounds__(256) void split_a(const float* __restrict__ A,
                                               unsigned short* __restrict__ hi,
                                               unsigned short* __restrict__ lo) {
  size_t i = ((size_t)blockIdx.x * 256 + threadIdx.x) * 4;
  float4 v = *(const float4*)(A + i);
  ushort4 h, l;
  h.x = f2bf(v.x); l.x = f2bf(v.x - bf2f(h.x));
  h.y = f2bf(v.y); l.y = f2bf(v.y - bf2f(h.y));
  h.z = f2bf(v.z); l.z = f2bf(v.z - bf2f(h.z));
  h.w = f2bf(v.w); l.w = f2bf(v.w - bf2f(h.w));
  *(ushort4*)(hi + i) = h;
  *(ushort4*)(lo + i) = l;
}

// ---------------- pre-pass 2: split + transpose B -> B_hiT, B_loT (bf16 [N][K])
__global__ __launch_bounds__(256) void split_bt(const float* __restrict__ B,
                                                unsigned short* __restrict__ hiT,
                                                unsigned short* __restrict__ loT) {
  __shared__ float tile[32][33];
  int n0 = blockIdx.x * 32, k0 = blockIdx.y * 32;
  int tx = threadIdx.x, ty = threadIdx.y;  // block (32,8)
#pragma unroll
  for (int i = 0; i < 32; i += 8)
    tile[ty + i][tx] = B[(size_t)(k0 + ty + i) * NDIM + n0 + tx];
  __syncthreads();
#pragma unroll
  for (int i = 0; i < 32; i += 8) {
    float x = tile[tx][ty + i];
    unsigned short h = f2bf(x);
    unsigned short l = f2bf(x - bf2f(h));
    size_t o = (size_t)(n0 + ty + i) * KDIM + k0 + tx;
    hiT[o] = h;
    loT[o] = l;
  }
}

// ---------------- main GEMM: 256x256, BK=64, 8 waves (2Mx4N), per-wave 128x64.
// Register-fragment pipeline: phase p reads cluster p+1's frags, MFMAs cluster p.
// 2 barriers + 2 counted vmcnt(2) per K-tile; ring-2 LDS 128 KiB, XOR-swizzled.
#define GLDS(gp, lp)                                              \
  __builtin_amdgcn_global_load_lds(                               \
      (const __attribute__((address_space(1))) void*)(gp),        \
      (__attribute__((address_space(3))) void*)(lp), 16, 0, 0)

#define BARRIER() asm volatile("s_barrier" ::: "memory")
#define WAITVM2() asm volatile("s_waitcnt vmcnt(2)" ::: "memory")
#define WAITVM0() asm volatile("s_waitcnt vmcnt(0)" ::: "memory")

#define MFMA_CL(MB, AV, BV)                                                      \
  __builtin_amdgcn_s_setprio(1);                                                 \
  _Pragma("unroll")                                                              \
  for (int m = 0; m < 4; ++m) {                                                  \
    _Pragma("unroll")                                                            \
    for (int n = 0; n < 4; ++n)                                                  \
      acc[MB + m][n] =                                                           \
          __builtin_amdgcn_mfma_f32_16x16x32_bf16(AV[m], BV[n], acc[MB + m][n], 0, 0, 0); \
  }                                                                              \
  __builtin_amdgcn_s_setprio(0)

__global__ __launch_bounds__(512, 2) void gemm_k3(
    const unsigned short* __restrict__ Ah, const unsigned short* __restrict__ Al,
    const unsigned short* __restrict__ BhT, const unsigned short* __restrict__ BlT,
    float* __restrict__ C) {
  __shared__ __align__(16) char lds_[131072];  // 128 KiB

  const int tid = threadIdx.x;
  const int l   = tid & 63;
  const int wv  = tid >> 6;   // 0..7
  const int wm  = wv >> 2;    // 0..1
  const int wn  = wv & 3;     // 0..3
  const int fr  = l & 15;
  const int fq  = l >> 4;

  // bijective XCD swizzle (256 blocks)
  const int bid = blockIdx.x;
  const int swz = (bid & 7) * 32 + (bid >> 3);
  const int bm = swz >> 4, bn = swz & 15;

  // staging lane geometry (linear LDS dest; inverse-swizzled global src)
  const int lG     = (l & 7) ^ (l >> 3);
  const int g_radd = 2 * (l >> 3) + (lG >> 2);
  const int g_col  = (lG & 3) * 16;
  const int row0a  = wv * 32;
  const int row0b  = wv * 32 + 16;

  // read lane geometry (swizzled ds_read; same involution)
  const int slot  = (((fr & 1) << 2) | fq) ^ ((fr >> 1) & 7);
  const int laneA = ((wm * 128 + fr) >> 1) * 128 + slot * 16;
  const int laneB = 65536 + ((wn * 64 + fr) >> 1) * 128 + slot * 16;

  const char* cAh = (const char*)Ah;
  const char* cAl = (const char*)Al;
  const char* cBh = (const char*)BhT;
  const char* cBl = (const char*)BlT;
  const size_t aoff = (size_t)(bm * 256) * 8192;
  const size_t boff = (size_t)(bn * 256) * 8192;

  f32x4 acc[8][4] = {};
  s16x8 aX[4], aY[4], b0[4], b1[4];

  // ---- prologue: stage tile 0 fully (order A0,B0,A1,B1), drain, read c0 ----
  {
    const char* As = cAh + aoff;
    const char* Bs = cBh + boff;
    GLDS(As + (size_t)(row0a + g_radd) * 8192 + g_col, lds_ + row0a * 64);
    GLDS(As + (size_t)(row0b + g_radd) * 8192 + g_col, lds_ + row0b * 64);
    GLDS(Bs + (size_t)(row0a + g_radd) * 8192 + g_col, lds_ + 65536 + row0a * 64);
    GLDS(Bs + (size_t)(row0b + g_radd) * 8192 + g_col, lds_ + 65536 + row0b * 64);
    GLDS(As + (size_t)(row0a + g_radd) * 8192 + 64 + g_col, lds_ + 16384 + row0a * 64);
    GLDS(As + (size_t)(row0b + g_radd) * 8192 + 64 + g_col, lds_ + 16384 + row0b * 64);
    GLDS(Bs + (size_t)(row0a + g_radd) * 8192 + 64 + g_col, lds_ + 65536 + 16384 + row0a * 64);
    GLDS(Bs + (size_t)(row0b + g_radd) * 8192 + 64 + g_col, lds_ + 65536 + 16384 + row0b * 64);
  }
  WAITVM0();
  BARRIER();
  {
    const char* pa = lds_ + laneA;
    const char* pb = lds_ + laneB;
#pragma unroll
    for (int m = 0; m < 4; ++m) aX[m] = *(const s16x8*)(pa + m * 1024);
#pragma unroll
    for (int n = 0; n < 4; ++n) b0[n] = *(const s16x8*)(pb + n * 1024);
  }

  for (int t = 0; t < NT - 1; ++t) {
    const int cur = t & 1;
    const char* pa = lds_ + cur * 32768 + laneA;
    const char* pb = lds_ + cur * 32768 + laneB;
    const int Tn = t + 1;
    const char* An = ((Tn < 64) ? cAh : (Tn < 128) ? cAl : cAh) + aoff;
    const char* Bn = ((Tn < 128) ? cBh : cBl) + boff;
    const size_t kb = (size_t)(Tn & 63) * 128;
    char* dA = lds_ + (Tn & 1) * 32768;
    char* dB = dA + 65536;
    const char* pa2 = dA + laneA;
    const char* pb2 = dA + laneB;

    // ---- ph0: read c1 (a[4..7],k0); stage A-ks0(t+1); MFMA c0(aX,b0) ----
#pragma unroll
    for (int m = 0; m < 4; ++m) aY[m] = *(const s16x8*)(pa + (4 + m) * 1024);
    GLDS(An + (size_t)(row0a + g_radd) * 8192 + kb + g_col, dA + row0a * 64);
    GLDS(An + (size_t)(row0b + g_radd) * 8192 + kb + g_col, dA + row0b * 64);
    MFMA_CL(0, aX, b0);

    // ---- ph1: drain A1,B1(t); read c2 (a[0..3],k1 + b k1); stage B-ks0(t+1); MFMA c1(aY,b0)
    WAITVM2();
    BARRIER();
#pragma unroll
    for (int m = 0; m < 4; ++m) aX[m] = *(const s16x8*)(pa + 16384 + m * 1024);
#pragma unroll
    for (int n = 0; n < 4; ++n) b1[n] = *(const s16x8*)(pb + 16384 + n * 1024);
    GLDS(Bn + (size_t)(row0a + g_radd) * 8192 + kb + g_col, dB + row0a * 64);
    GLDS(Bn + (size_t)(row0b + g_radd) * 8192 + kb + g_col, dB + row0b * 64);
    MFMA_CL(4, aY, b0);

    // ---- ph2: read c3 (a[4..7],k1); stage A-ks1(t+1); MFMA c2(aX,b1) ----
#pragma unroll
    for (int m = 0; m < 4; ++m) aY[m] = *(const s16x8*)(pa + 16384 + (4 + m) * 1024);
    GLDS(An + (size_t)(row0a + g_radd) * 8192 + kb + 64 + g_col, dA + 16384 + row0a * 64);
    GLDS(An + (size_t)(row0b + g_radd) * 8192 + kb + 64 + g_col, dA + 16384 + row0b * 64);
    MFMA_CL(0, aX, b1);

    // ---- ph3: drain A0,B0(t+1); read t+1 c0 from buf[nxt]; stage B-ks1(t+1); MFMA c3(aY,b1)
    WAITVM2();
    BARRIER();
#pragma unroll
    for (int m = 0; m < 4; ++m) aX[m] = *(const s16x8*)(pa2 + m * 1024);
#pragma unroll
    for (int n = 0; n < 4; ++n) b0[n] = *(const s16x8*)(pb2 + n * 1024);
    GLDS(Bn + (size_t)(row0a + g_radd) * 8192 + kb + 64 + g_col, dB + 16384 + row0a * 64);
    GLDS(Bn + (size_t)(row0b + g_radd) * 8192 + kb + 64 + g_col, dB + 16384 + row0b * 64);
    MFMA_CL(4, aY, b1);
  }

  // ---- peeled tail: t = NT-1 (no staging, no next-tile reads) ----
  {
    const int cur = (NT - 1) & 1;
    const char* pa = lds_ + cur * 32768 + laneA;
    const char* pb = lds_ + cur * 32768 + laneB;
    // ph0
#pragma unroll
    for (int m = 0; m < 4; ++m) aY[m] = *(const s16x8*)(pa + (4 + m) * 1024);
    MFMA_CL(0, aX, b0);
    // ph1 — drain this tile's ks1 units
    WAITVM0();
    BARRIER();
#pragma unroll
    for (int m = 0; m < 4; ++m) aX[m] = *(const s16x8*)(pa + 16384 + m * 1024);
#pragma unroll
    for (int n = 0; n < 4; ++n) b1[n] = *(const s16x8*)(pb + 16384 + n * 1024);
    MFMA_CL(4, aY, b0);
    // ph2
#pragma unroll
    for (int m = 0; m < 4; ++m) aY[m] = *(const s16x8*)(pa + 16384 + (4 + m) * 1024);
    MFMA_CL(0, aX, b1);
    // ph3
    MFMA_CL(4, aY, b1);
  }

  // ---- epilogue: C/D layout col=lane&15, row=(lane>>4)*4+j ----
  float* Cp = C + (size_t)(bm * 256 + wm * 128) * NDIM + (bn * 256 + wn * 64);
#pragma unroll
  for (int m = 0; m < 8; ++m)
#pragma unroll
    for (int n = 0; n < 4; ++n)
#pragma unroll
      for (int j = 0; j < 4; ++j)
        Cp[(size_t)(m * 16 + fq * 4 + j) * NDIM + n * 16 + fr] = acc[m][n][j];
}

// ---------------- fallback: plain fp32 tiled GEMM (ws too small) ----------------
__global__ __launch_bounds__(1024) void gemm_fp32_fallback(const float* __restrict__ A,
                                                           const float* __restrict__ B,
                                                           float* __restrict__ C) {
  __shared__ float As[32][33];
  __shared__ float Bs[32][33];
  int tx = threadIdx.x, ty = threadIdx.y;
  int row = blockIdx.y * 32 + ty, colg = blockIdx.x * 32 + tx;
  float acc = 0.f;
  for (int k0 = 0; k0 < KDIM; k0 += 32) {
    As[ty][tx] = A[(size_t)row * KDIM + k0 + tx];
    Bs[ty][tx] = B[(size_t)(k0 + ty) * NDIM + colg];
    __syncthreads();
#pragma unroll 8
    for (int kk = 0; kk < 32; ++kk) acc += As[ty][kk] * Bs[kk][tx];
    __syncthreads();
  }
  C[(size_t)row * NDIM + colg] = acc;
}

extern "C" void kernel_launch(void* const* d_in, const int* in_sizes, int n_in,
                              void* d_out, int out_size, void* d_ws, size_t ws_size,
                              hipStream_t stream) {
  const float* A = (const float*)d_in[0];
  const float* B = (const float*)d_in[1];
  float* C = (float*)d_out;

  const size_t elems = (size_t)MDIM * KDIM;
  const size_t need = 4 * elems * sizeof(unsigned short);  // 128 MB
  if (ws_size < need) {
    gemm_fp32_fallback<<<dim3(NDIM / 32, MDIM / 32), dim3(32, 32), 0, stream>>>(A, B, C);
    return;
  }

  unsigned short* Ah  = (unsigned short*)d_ws;
  unsigned short* Al  = Ah + elems;
  unsigned short* BhT = Al + elems;
  unsigned short* BlT = BhT + elems;

  split_a<<<(int)(elems / (256 * 4)), 256, 0, stream>>>(A, Ah, Al);
  split_bt<<<dim3(NDIM / 32, KDIM / 32), dim3(32, 8), 0, stream>>>(B, BhT, BlT);
  gemm_k3<<<dim3(256), dim3(512), 0, stream>>>(Ah, Al, BhT, BlT, C);
}